// Round 9
// baseline (214.661 us; speedup 1.0000x reference)
//
#include <hip/hip_runtime.h>

typedef unsigned short u16;
typedef unsigned int u32;
typedef __bf16 bf16x8 __attribute__((ext_vector_type(8)));
typedef __bf16 bf16x2 __attribute__((ext_vector_type(2)));
typedef float f32x4 __attribute__((ext_vector_type(4)));

#define QSCALE 0.18033688011112f  // 0.125 * log2(e): folded into Q so p = 2^s

__device__ __forceinline__ u16 f2bf(float f) {
  u32 u = __builtin_bit_cast(u32, f);
  u += 0x7fffu + ((u >> 16) & 1u);   // RNE
  return (u16)(u >> 16);
}

// packed f32x2 -> bf16x2 (RNE), emits v_cvt_pk_bf16_f32 on gfx950
__device__ __forceinline__ u32 pkbf(float a, float b) {
  bf16x2 t = {(__bf16)a, (__bf16)b};
  return __builtin_bit_cast(u32, t);
}

__device__ __forceinline__ bf16x8 as_bf16x8(uint4 v) {
  return __builtin_bit_cast(bf16x8, v);
}

// async global->LDS, 16B per lane; LDS dest = wave-uniform base + lane*16
__device__ __forceinline__ void async16(const void* g, void* l) {
  __builtin_amdgcn_global_load_lds(
      (__attribute__((address_space(1))) void*)(g),
      (__attribute__((address_space(3))) void*)(l), 16, 0, 0);
}

// ---------------- merged prep: cast xq/xkv to bf16 + transpose-cast 3 weights
__global__ void prep_kernel(const float* __restrict__ xq, const float* __restrict__ xkv,
                            const float* __restrict__ Wq, const float* __restrict__ Wkv,
                            const float* __restrict__ Wo,
                            u16* __restrict__ Xq16, u16* __restrict__ Xkv16,
                            u16* __restrict__ WqT, u16* __restrict__ WkvT,
                            u16* __restrict__ WoT) {
  const int bid = blockIdx.x, tid = threadIdx.x;
  if (bid < 8192) {
    int i = bid * 256 + tid;
    const float* s; u16* d; int j;
    if (i < 1048576) { s = xq; d = Xq16; j = i; }
    else             { s = xkv; d = Xkv16; j = i - 1048576; }
    float4 v = ((const float4*)s)[j];
    ushort4 o;
    o.x = f2bf(v.x); o.y = f2bf(v.y); o.z = f2bf(v.z); o.w = f2bf(v.w);
    ((ushort4*)d)[j] = o;
    return;
  }
  const int b2 = bid - 8192;
  const int z = b2 >> 11, rem = b2 & 2047;
  const int by = rem >> 6, bx = rem & 63;
  const float* src; u16* dst; int Nd;
  if (z == 0)      { src = Wq;  dst = WqT;  Nd = 1024; }
  else if (z == 1) { src = Wkv; dst = WkvT; Nd = 2048; }
  else             { src = Wo;  dst = WoT;  Nd = 1024; }
  const int n0 = bx * 32, k0 = by * 32;
  if (n0 >= Nd) return;
  __shared__ float tile[32][33];
  const int tx = tid & 31, ty = tid >> 5;  // 32 x 8
#pragma unroll
  for (int j = 0; j < 4; ++j)
    tile[ty + 8 * j][tx] = src[(size_t)(k0 + ty + 8 * j) * Nd + n0 + tx];
  __syncthreads();
#pragma unroll
  for (int j = 0; j < 4; ++j)
    dst[(size_t)(n0 + ty + 8 * j) * 1024 + k0 + tx] = f2bf(tile[tx][ty + 8 * j]);
}

// ---------------------------------------------------------------- GEMM core
// OPERAND-SWAPPED MFMA: acc[mi][ni] = mfma(bfr[ni], af[mi], ..) computes the
// C^T layout: lane l16 = A-row (m), reg quad*4+r = B-col (n) -> each lane's
// 4 acc values are CONSECUTIVE output columns => vectorized coalesced stores.
template <int MI>
static __device__ __forceinline__ void gemm_core(
    const u16* __restrict__ A, const u16* __restrict__ Bt, int m0,
    uint4* sA, uint4* sB, f32x4 (*acc)[4]) {
  const int tid = threadIdx.x;
  const int wv = tid >> 6, lane = tid & 63;
  const int quad = lane >> 4, l16 = lane & 15;
  const int wm = (wv >> 1) * (MI * 16), wn = (wv & 1) * 64;

  const int ib0 = wv * 128 + lane, ib1 = ib0 + 64;      // B: 512 slots
  const int br0 = ib0 >> 2, bc0 = (ib0 & 3) ^ ((br0 >> 1) & 3);
  const int br1 = ib1 >> 2, bc1 = (ib1 & 3) ^ ((br1 >> 1) & 3);
  const u16* gB0 = Bt + (size_t)br0 * 1024 + bc0 * 8;
  const u16* gB1 = Bt + (size_t)br1 * 1024 + bc1 * 8;

  const int ia0 = wv * (MI * 32) + lane;                // A: MI*128 slots
  const int ar0 = ia0 >> 2, ac0 = (ia0 & 3) ^ ((ar0 >> 1) & 3);
  const u16* gA0 = A + (size_t)(m0 + ar0) * 1024 + ac0 * 8;
  const int ia1 = ia0 + 64;
  const int ar1 = ia1 >> 2, ac1 = (ia1 & 3) ^ ((ar1 >> 1) & 3);
  const u16* gA1 = A + (size_t)(m0 + ar1) * 1024 + ac1 * 8;
  uint4* sAw = sA + wv * (MI * 32);
  uint4* sBw = sB + wv * 128;

  for (int k0 = 0; k0 < 1024; k0 += 32) {
    __syncthreads();
    async16(gA0 + k0, sAw);
    if (MI == 4) async16(gA1 + k0, sAw + 64);
    async16(gB0 + k0, sBw);
    async16(gB1 + k0, sBw + 64);
    __syncthreads();

    bf16x8 af[MI], bfr[4];
#pragma unroll
    for (int mi = 0; mi < MI; ++mi) {
      int r = wm + mi * 16 + l16;
      af[mi] = as_bf16x8(sA[r * 4 + (quad ^ ((r >> 1) & 3))]);
    }
#pragma unroll
    for (int ni = 0; ni < 4; ++ni) {
      int r = wn + ni * 16 + l16;
      bfr[ni] = as_bf16x8(sB[r * 4 + (quad ^ ((r >> 1) & 3))]);
    }
#pragma unroll
    for (int mi = 0; mi < MI; ++mi)
#pragma unroll
      for (int ni = 0; ni < 4; ++ni)
        acc[mi][ni] = __builtin_amdgcn_mfma_f32_16x16x32_bf16(
            bfr[ni], af[mi], acc[mi][ni], 0, 0, 0);   // swapped operands
  }
}

// ------------------------------------- fused Q/K/V projection GEMM (N = 3072 virtual)
// Swapped layout: lane holds (row m = ..+l16, cols n = gnb..gnb+3).
// Q/K: ushort4 stores (32B segments). V^T: 4 row-stores of 16-lane 32B segments.
__global__ __launch_bounds__(256, 3) void gemm_qkv(
    const u16* __restrict__ Xq, const u16* __restrict__ Xkv,
    const u16* __restrict__ WqT, const u16* __restrict__ WkvT,
    const float* __restrict__ bq, const float* __restrict__ bkv,
    u16* __restrict__ Qd, u16* __restrict__ Kd, u16* __restrict__ Vd) {
  __shared__ uint4 sA[512], sB[512];
  f32x4 acc[4][4] = {};
  const int n0 = blockIdx.x * 128, m0 = blockIdx.y * 128;
  const u16* A = (n0 < 1024) ? Xq : Xkv;
  const u16* Bt = (n0 < 1024) ? (WqT + (size_t)n0 * 1024)
                              : (WkvT + (size_t)(n0 - 1024) * 1024);
  const float* bias = (n0 < 1024) ? (bq + n0) : (bkv + (n0 - 1024));
  gemm_core<4>(A, Bt, m0, sA, sB, acc);

  const int tid = threadIdx.x, wv = tid >> 6, lane = tid & 63;
  const int quad = lane >> 4, l16 = lane & 15;
  const int wm = (wv >> 1) * 64, wn = (wv & 1) * 64;
  const int bb = m0 >> 11;
#pragma unroll
  for (int ni = 0; ni < 4; ++ni) {
    const int gnb = n0 + wn + ni * 16 + quad * 4;   // 4 consecutive virtual cols
    const f32x4 bv = *(const f32x4*)(bias + wn + ni * 16 + quad * 4);
    if (gnb < 1024) {                               // Q plain, pre-scaled
#pragma unroll
      for (int mi = 0; mi < 4; ++mi) {
        const int gm = m0 + wm + mi * 16 + l16;
        f32x4 v = (acc[mi][ni] + bv) * QSCALE;
        uint2 pk = {pkbf(v[0], v[1]), pkbf(v[2], v[3])};
        *(uint2*)(Qd + (size_t)gm * 1024 + gnb) = pk;
      }
    } else if (gnb < 2048) {                        // K plain
#pragma unroll
      for (int mi = 0; mi < 4; ++mi) {
        const int gm = m0 + wm + mi * 16 + l16;
        f32x4 v = acc[mi][ni] + bv;
        uint2 pk = {pkbf(v[0], v[1]), pkbf(v[2], v[3])};
        *(uint2*)(Kd + (size_t)gm * 1024 + (gnb - 1024)) = pk;
      }
    } else {                                        // V^T: [bh][dh][skv]
      const int col = gnb - 2048, hh = col >> 6, dv = col & 63;
      u16* base = Vd + ((size_t)(bb * 16 + hh) * 64 + dv) * 2048
                    + (m0 & 2047) + wm + l16;
#pragma unroll
      for (int mi = 0; mi < 4; ++mi) {
        f32x4 v = acc[mi][ni] + bv;
#pragma unroll
        for (int r = 0; r < 4; ++r)
          base[(size_t)r * 2048 + mi * 16] = f2bf(v[r]);
      }
    }
  }
}

// ---------------------------------------------------------------- flash attention
// R8 core (256 thr, BQ=128, BKV=64, dbuf staging, ONE barrier/iter, XCD-grouped
// flat grid) + KV-PARTITION: wave (qh,kh) computes 64 q x 32 kv. K/V frag reads
// drop 20->12 b128/wave-iter (was 4x redundant across waves). kh-pairs merge
// additive partials (sum pV, sum p) through LDS once at the end (no max-sub).
__global__ __launch_bounds__(256, 2) void flash_attn(
    const u16* __restrict__ Q, const u16* __restrict__ K,
    const u16* __restrict__ V, u16* __restrict__ O) {
  __shared__ uint4 sK[2][512];              // 64 kv x 64 dh, x2 buffers
  __shared__ uint4 sV[2][512];              // 64 dh x 64 kv (V^T), x2
  __shared__ __align__(16) u16 sP[4][64][40];   // per-wave 64q x 32kv, pad 40

  const int tid = threadIdx.x;
  const int wv = tid >> 6, lane = tid & 63;
  const int quad = lane >> 4, l16 = lane & 15;
  const int qh = wv >> 1, kh = wv & 1;
  const int hb = blockIdx.x & 31;           // fast dim: (h, b) -> fixes XCD
  const int q0 = (blockIdx.x >> 5) * 128;   // slow dim: q-block
  const int h = hb & 15, bz = hb >> 4;

  const u16* Qb = Q + ((size_t)(bz * 2048 + q0 + qh * 64)) * 1024 + h * 64;
  const u16* Kb = K + ((size_t)(bz * 2048)) * 1024 + h * 64;
  const u16* Vb = V + ((size_t)(bz * 16 + h)) * 64 * 2048;

  // Q frags: 64 q-rows resident (A-layout: m=l16, k=quad*8+j)
  bf16x8 qf[4][2];
#pragma unroll
  for (int rb = 0; rb < 4; ++rb) {
    const uint4* qp = (const uint4*)(Qb + (size_t)(rb * 16 + l16) * 1024);
    qf[rb][0] = as_bf16x8(qp[quad]);
    qf[rb][1] = as_bf16x8(qp[4 + quad]);
  }

  f32x4 oacc[4][4] = {};
  f32x4 lsum[4] = {};
  const uint4 ones4 = {0x3F803F80u, 0x3F803F80u, 0x3F803F80u, 0x3F803F80u};
  const bf16x8 ones = as_bf16x8(ones4);

  // staging (identical to R8): each wave stages a quarter of K and V tiles
  const int i0 = wv * 128 + lane, i1 = i0 + 64;
  const int kr0 = i0 >> 3, kr1 = i1 >> 3;
  const int kck0 = (i0 & 7) ^ ((i0 >> 5) & 7);   // K: slot c holds chunk c^((row>>2)&7)
  const int kck1 = (i1 & 7) ^ ((i1 >> 5) & 7);
  const int vck0 = (i0 & 7) ^ (kr0 & 7);         // V: slot c holds chunk c^(row&7)
  const int vck1 = (i1 & 7) ^ (kr1 & 7);
  const u16* gK0 = Kb + (size_t)kr0 * 1024 + kck0 * 8;
  const u16* gK1 = Kb + (size_t)kr1 * 1024 + kck1 * 8;
  const u16* gV0 = Vb + (size_t)kr0 * 2048 + vck0 * 8;
  const u16* gV1 = Vb + (size_t)kr1 * 2048 + vck1 * 8;
  const int wo = wv * 128;

  // prologue: tile 0 -> buffer 0
  async16(gK0, &sK[0][wo]);
  async16(gK1, &sK[0][wo + 64]);
  async16(gV0, &sV[0][wo]);
  async16(gV1, &sV[0][wo + 64]);

  for (int t = 0; t < 32; ++t) {
    const int cur = t & 1;
    __syncthreads();   // drains loads for tile t (issued one iter ago)
    if (t < 31) {
      const int nxt = cur ^ 1;
      const size_t ko = (size_t)(t + 1) * 64 * 1024;
      const int vo = (t + 1) * 64;
      async16(gK0 + ko, &sK[nxt][wo]);
      async16(gK1 + ko, &sK[nxt][wo + 64]);
      async16(gV0 + vo, &sV[nxt][wo]);
      async16(gV1 + vo, &sV[nxt][wo + 64]);
    }
    const uint4* K_ = sK[cur];
    const uint4* V_ = sV[cur];

    // K frags: this wave's kv-half only, interleave kv = kh*32 + 2*l16 + ni
    bf16x8 bK[2][2];
#pragma unroll
    for (int ni = 0; ni < 2; ++ni) {
      int rr = kh * 32 + 2 * l16 + ni;
      int sw = (rr >> 2) & 7;
      bK[ni][0] = as_bf16x8(K_[rr * 8 + (quad ^ sw)]);
      bK[ni][1] = as_bf16x8(K_[rr * 8 + ((4 + quad) ^ sw)]);
    }
    // V frags: kv-half k-slice, chunk = kh*4+quad
    bf16x8 vf[4];
#pragma unroll
    for (int ni = 0; ni < 4; ++ni) {
      int vv = ni * 16 + l16;
      vf[ni] = as_bf16x8(V_[vv * 8 + ((kh * 4 + quad) ^ (vv & 7))]);
    }

    // QK + exp2 + pack: per rb, cols kv_local = 2*l16 + {0,1} -> one b32 write
#pragma unroll
    for (int rb = 0; rb < 4; ++rb) {
      f32x4 s0 = {0.f, 0.f, 0.f, 0.f}, s1 = {0.f, 0.f, 0.f, 0.f};
      s0 = __builtin_amdgcn_mfma_f32_16x16x32_bf16(qf[rb][0], bK[0][0], s0, 0, 0, 0);
      s0 = __builtin_amdgcn_mfma_f32_16x16x32_bf16(qf[rb][1], bK[0][1], s0, 0, 0, 0);
      s1 = __builtin_amdgcn_mfma_f32_16x16x32_bf16(qf[rb][0], bK[1][0], s1, 0, 0, 0);
      s1 = __builtin_amdgcn_mfma_f32_16x16x32_bf16(qf[rb][1], bK[1][1], s1, 0, 0, 0);
#pragma unroll
      for (int r = 0; r < 4; ++r)
        *(u32*)&sP[wv][rb * 16 + quad * 4 + r][l16 * 2] =
            pkbf(exp2f(s0[r]), exp2f(s1[r]));
    }
    // sP wave-private: lgkmcnt ordering suffices, no barrier

    // PV over this wave's 32-kv half (K=32 -> one MFMA per (rb,ni))
#pragma unroll
    for (int rb = 0; rb < 4; ++rb) {
      bf16x8 pf = as_bf16x8(*(const uint4*)&sP[wv][rb * 16 + l16][quad * 8]);
      lsum[rb] = __builtin_amdgcn_mfma_f32_16x16x32_bf16(pf, ones, lsum[rb], 0, 0, 0);
#pragma unroll
      for (int ni = 0; ni < 4; ++ni)
        oacc[rb][ni] = __builtin_amdgcn_mfma_f32_16x16x32_bf16(pf, vf[ni], oacc[rb][ni], 0, 0, 0);
    }
  }

  // ---- kh-pair reduction through LDS (partials are additive), then store ----
  __syncthreads();                       // all staging/frag reads done
  float* xo = (float*)sK;                // 32 KB = 8192 floats (16 KB per qh)
  float* xl = (float*)sP;                // lsum exchange (2 KB per qh)
  if (kh) {
#pragma unroll
    for (int rb = 0; rb < 4; ++rb) {
#pragma unroll
      for (int ni = 0; ni < 4; ++ni)
        *(f32x4*)&xo[qh * 4096 + (rb * 4 + ni) * 256 + lane * 4] = oacc[rb][ni];
      *(f32x4*)&xl[qh * 1024 + rb * 256 + lane * 4] = lsum[rb];
    }
  }
  __syncthreads();
  if (!kh) {
#pragma unroll
    for (int rb = 0; rb < 4; ++rb) {
      f32x4 lt = lsum[rb] + *(const f32x4*)&xl[qh * 1024 + rb * 256 + lane * 4];
      f32x4 ot[4];
#pragma unroll
      for (int ni = 0; ni < 4; ++ni)
        ot[ni] = oacc[rb][ni] +
                 *(const f32x4*)&xo[qh * 4096 + (rb * 4 + ni) * 256 + lane * 4];
      u16* Ob = O + ((size_t)(bz * 2048 + q0 + qh * 64 + rb * 16 + quad * 4)) * 1024
                  + h * 64;
#pragma unroll
      for (int r = 0; r < 4; ++r) {
        float rl = 1.0f / lt[r];
#pragma unroll
        for (int ni = 0; ni < 4; ++ni)
          Ob[(size_t)r * 1024 + ni * 16 + l16] = f2bf(ot[ni][r] * rl);
      }
    }
  }
}

// ---------------------------------------------------------------- output projection
// Swapped layout -> perfectly coalesced float4 stores (64B lines).
__global__ __launch_bounds__(256, 2) void gemm_out(
    const u16* __restrict__ A, const u16* __restrict__ Bt,
    const float* __restrict__ bias, float* __restrict__ C) {
  __shared__ uint4 sA[256], sB[512];
  f32x4 acc[2][4] = {};
  const int n0 = blockIdx.x * 128, m0 = blockIdx.y * 64;
  gemm_core<2>(A, Bt + (size_t)n0 * 1024, m0, sA, sB, acc);

  const int tid = threadIdx.x, wv = tid >> 6, lane = tid & 63;
  const int quad = lane >> 4, l16 = lane & 15;
  const int wm = (wv >> 1) * 32, wn = (wv & 1) * 64;
#pragma unroll
  for (int ni = 0; ni < 4; ++ni) {
    const int gnb = n0 + wn + ni * 16 + quad * 4;
    const f32x4 bv = *(const f32x4*)(bias + wn + ni * 16 + quad * 4 + n0);
#pragma unroll
    for (int mi = 0; mi < 2; ++mi) {
      const int gm = m0 + wm + mi * 16 + l16;
      *(f32x4*)(C + (size_t)gm * 1024 + gnb) = acc[mi][ni] + bv;
    }
  }
}

extern "C" void kernel_launch(void* const* d_in, const int* in_sizes, int n_in,
                              void* d_out, int out_size, void* d_ws, size_t ws_size,
                              hipStream_t stream) {
  const float* xq  = (const float*)d_in[0];
  const float* xkv = (const float*)d_in[1];
  const float* Wq  = (const float*)d_in[2];
  const float* bq  = (const float*)d_in[3];
  const float* Wkv = (const float*)d_in[4];
  const float* bkv = (const float*)d_in[5];
  const float* Wo  = (const float*)d_in[6];
  const float* bo  = (const float*)d_in[7];
  float* out = (float*)d_out;

  char* p = (char*)d_ws;                       // 56 MiB total
  u16* Xq16  = (u16*)p; p += (size_t)8 << 20;  // [4096][1024] bf16
  u16* Xkv16 = (u16*)p; p += (size_t)8 << 20;
  u16* WqT   = (u16*)p; p += (size_t)2 << 20;  // [1024][1024]
  u16* WkvT  = (u16*)p; p += (size_t)4 << 20;  // [2048][1024]
  u16* WoT   = (u16*)p; p += (size_t)2 << 20;
  u16* Q16   = (u16*)p; p += (size_t)8 << 20;  // plain [4096][1024], pre-scaled
  u16* K16   = (u16*)p; p += (size_t)8 << 20;  // plain [4096][1024]
  u16* Vt16  = (u16*)p; p += (size_t)8 << 20;  // [bh][dh][skv]
  u16* O16   = (u16*)p; p += (size_t)8 << 20;  // plain [4096][1024]

  prep_kernel<<<14336, 256, 0, stream>>>(xq, xkv, Wq, Wkv, Wo,
                                         Xq16, Xkv16, WqT, WkvT, WoT);
  gemm_qkv<<<dim3(24, 32), 256, 0, stream>>>(Xq16, Xkv16, WqT, WkvT, bq, bkv,
                                             Q16, K16, Vt16);
  flash_attn<<<512, 256, 0, stream>>>(Q16, K16, Vt16, O16);
  gemm_out<<<dim3(8, 64), 256, 0, stream>>>(O16, WoT, bo, out);
}